// Round 5
// baseline (478.875 us; speedup 1.0000x reference)
//
#include <hip/hip_runtime.h>
#include <hip/hip_fp16.h>
#include <math.h>

#define N_NODES   100000
#define N_EDGES   1600000
#define NDIM      64
#define H         128
#define NUM_LAYERS 3
#define NUM_CLASSES 6
#define NUM_GRAPHS 512
#define LN_EPS    1e-5f
#define NBKT      391           // ceil(N_NODES / 256)
#define BPAD      136           // LDS row stride (halves)

typedef _Float16 f16x8 __attribute__((ext_vector_type(8)));
typedef float    f32x4 __attribute__((ext_vector_type(4)));

// ---------- helpers ----------
__device__ __forceinline__ int idx_at(const int* raw, int is64, int i) {
    return is64 ? raw[2 * (long long)i] : raw[i];
}
__device__ __forceinline__ int lower_bound(const int* a, int n, int v) {
    int lo = 0, hi = n;
    while (lo < hi) { int m = (lo + hi) >> 1; if (a[m] < v) lo = m + 1; else hi = m; }
    return lo;
}

// 16B gather: SGPR base + 32-bit voffset, asm-pinned issue order.
__device__ __forceinline__ f32x4 gload16(const __half* __restrict__ base, int voff) {
    f32x4 r;
    asm volatile("global_load_dwordx4 %0, %1, %2"
                 : "=v"(r) : "v"(voff), "s"(base));
    return r;
}

// ---------- dtype detection + init (bcnt zero + zero-row for aggr padding) ----------
__global__ void k_detect(const int* eraw, const int* braw, int* flags,
                         int* bcnt, float* gate_z) {
    int i = blockIdx.x * blockDim.x + threadIdx.x;
    if (i < 512) bcnt[i] = 0;
    if (i < 64) gate_z[i] = 0.f;    // 256 B zero row (gate buffer dead until k_gate_mfma)
    if (i == 0) {
        int e64 = 1;
        for (int k = 1; k < 128; k += 2) if (eraw[k] != 0) { e64 = 0; break; }
        flags[0] = e64;
        flags[1] = (braw[N_NODES - 1] == 0) ? 1 : 0;
    }
}

__global__ void k_conv_batch(const int* braw, const int* flags, int* batch32) {
    int i = blockIdx.x * blockDim.x + threadIdx.x;
    if (i < N_NODES) batch32[i] = idx_at(braw, flags[1], i);
}

// ---------- bucket histogram (512 buckets by dst>>8), LDS-aggregated ----------
__global__ __launch_bounds__(256) void k_bhist(const int* eraw, const int* flags, int* bcnt) {
    __shared__ int c[512];
    int tid = threadIdx.x;
    for (int i = tid; i < 512; i += 256) c[i] = 0;
    __syncthreads();
    int f = flags[0];
    int stride = gridDim.x * 256;
    for (int e = blockIdx.x * 256 + tid; e < N_EDGES; e += stride) {
        int d = idx_at(eraw, f, N_EDGES + e);
        atomicAdd(&c[d >> 8], 1);
    }
    __syncthreads();
    for (int i = tid; i < 512; i += 256) if (c[i]) atomicAdd(&bcnt[i], c[i]);
}

// ---------- scan of 512 bucket counts -> boff[513], bcursor ----------
__global__ void k_bscan(const int* bcnt, int* boff, int* bcursor) {
    __shared__ int sh[512];
    int tid = threadIdx.x;     // 512 threads
    int v = bcnt[tid];
    sh[tid] = v;
    __syncthreads();
    for (int off = 1; off < 512; off <<= 1) {
        int u = (tid >= off) ? sh[tid - off] : 0;
        __syncthreads();
        sh[tid] += u;
        __syncthreads();
    }
    int excl = sh[tid] - v;
    boff[tid] = excl;
    bcursor[tid] = excl;
    if (tid == 511) boff[512] = sh[511];
}

// ---------- phase A: scatter packed records, LDS-staged coalesced flush ----------
#define EPB 4096
__global__ __launch_bounds__(256) void k_bucket(const int* eraw, const int* flags,
                                                int* bcursor, unsigned int* br) {
    __shared__ int cnt[512];
    __shared__ int excl[512];
    __shared__ int resv[512];
    __shared__ int lcur[512];
    __shared__ int psum[256];
    __shared__ unsigned int srec[EPB];
    __shared__ unsigned short sbkt[EPB];
    int tid = threadIdx.x;
    int f = flags[0];
    int base = blockIdx.x * EPB;
    int se[16], de[16];
#pragma unroll
    for (int j = 0; j < 16; ++j) {
        int e = base + j * 256 + tid;
        if (e < N_EDGES) {
            se[j] = idx_at(eraw, f, e);
            de[j] = idx_at(eraw, f, N_EDGES + e);
        } else de[j] = -1;
    }
    for (int i = tid; i < 512; i += 256) cnt[i] = 0;
    __syncthreads();
#pragma unroll
    for (int j = 0; j < 16; ++j)
        if (de[j] >= 0) atomicAdd(&cnt[de[j] >> 8], 1);
    __syncthreads();
    int b0 = cnt[2 * tid], b1 = cnt[2 * tid + 1];
    psum[tid] = b0 + b1;
    __syncthreads();
    for (int off = 1; off < 256; off <<= 1) {
        int u = (tid >= off) ? psum[tid - off] : 0;
        __syncthreads();
        psum[tid] += u;
        __syncthreads();
    }
    int pex = psum[tid] - (b0 + b1);     // exclusive prefix of bucket 2*tid
    excl[2 * tid] = pex;
    excl[2 * tid + 1] = pex + b0;
    lcur[2 * tid] = pex;
    lcur[2 * tid + 1] = pex + b0;
    resv[2 * tid]     = b0 ? atomicAdd(&bcursor[2 * tid], b0) : 0;
    resv[2 * tid + 1] = b1 ? atomicAdd(&bcursor[2 * tid + 1], b1) : 0;
    __syncthreads();
#pragma unroll
    for (int j = 0; j < 16; ++j)
        if (de[j] >= 0) {
            int b = de[j] >> 8;
            int slot = atomicAdd(&lcur[b], 1);
            srec[slot] = ((unsigned int)(de[j] & 255) << 24) | (unsigned int)se[j];
            sbkt[slot] = (unsigned short)b;
        }
    __syncthreads();
    int vtot = psum[255];
    for (int s2 = tid; s2 < vtot; s2 += 256) {
        int b = sbkt[s2];
        br[resv[b] + (s2 - excl[b])] = srec[s2];
    }
}

// ---------- CSR tail -> PADDED implicit-stride layout ----------
// colp[node*64 + group*16 + j] holds byte offsets (src*256); padding slots hold
// zoff (zero-row). Edge rank r maps to slot (r&3)*16 + (r>>2) so a node's first
// 32 edges live in j<8 (chunk1) of each group. rowptr becomes IMPLICIT (node*64);
// only deg[node] is stored (mean denominator + rare chunk2 trigger). This kills
// the old intra-bucket scan AND all clamps/selects in k_aggr.
__global__ __launch_bounds__(256) void k_csr_tail(const unsigned int* br, const int* boff,
                                                  int* degarr, int* colp, int zoff) {
    __shared__ int d256[256];
    __shared__ int cbuf[256 * 64];   // 64 KB padded tile
    int b = blockIdx.x;
    int tid = threadIdx.x;
    int lo = boff[b], hi = boff[b + 1];
    int nloc = N_NODES - (b << 8);
    if (nloc > 256) nloc = 256;
    int tot4 = (nloc * 64) >> 2;
    d256[tid] = 0;
    int4 z4 = make_int4(zoff, zoff, zoff, zoff);
    for (int i = tid; i < tot4; i += 256) ((int4*)cbuf)[i] = z4;
    __syncthreads();
    for (int i = lo + tid; i < hi; i += 256) {
        unsigned int r = br[i];
        int local = r >> 24;
        int p = atomicAdd(&d256[local], 1);
        if (p < 64) {
            int slot = (local << 6) + ((p & 3) << 4) + (p >> 2);
            cbuf[slot] = (int)(r & 0xFFFFFF) << 8;
        }
    }
    __syncthreads();
    int node = (b << 8) + tid;
    if (node < N_NODES) degarr[node] = d256[tid];
    int4* dst4 = (int4*)colp + ((size_t)b << 12);
    for (int i = tid; i < tot4; i += 256) dst4[i] = ((const int4*)cbuf)[i];
}

// ---------- weight prep ----------
__global__ void k_prepw(const float* __restrict__ lin_l_w, const float* __restrict__ lin_r_w,
                        const float* __restrict__ gate_w1,
                        __half* __restrict__ W16t, __half* __restrict__ W16g) {
    int i = blockIdx.x * 256 + threadIdx.x;
    if (i < NUM_LAYERS * 128 * 256) {
        int l = i >> 15;
        int rem = i & 32767;
        int n = rem >> 8;
        int k = rem & 255;
        float v = (k < 128) ? lin_l_w[(size_t)l * 16384 + k * 128 + n]
                            : lin_r_w[(size_t)l * 16384 + (k - 128) * 128 + n];
        W16t[(size_t)l * 32768 + n * 256 + k] = __float2half(v);
    } else if (i < NUM_LAYERS * 128 * 256 + 64 * 128) {
        int idx = i - NUM_LAYERS * 128 * 256;
        int n = idx >> 7;
        int k = idx & 127;
        W16g[n * 128 + k] = __float2half(gate_w1[k * 64 + n]);
    }
}

// ---------- tiled fp32 GEMM (COLS=128): h16 = fp16(relu(A[n,K] @ W + bias)) ----------
__global__ __launch_bounds__(256) void k_gemm_proj(const float* __restrict__ A,
                                                   const float* __restrict__ W,
                                                   const float* __restrict__ bias,
                                                   __half* __restrict__ C16,
                                                   int nrows, int K) {
    __shared__ float As_t[32][68];
    __shared__ float Ws[32 * 128];
    int tid = threadIdx.x;
    int row0 = blockIdx.x * 64;
    int tr = tid >> 4;
    int tc = tid & 15;
    int c0 = tc * 8;
    float acc[4][8];
#pragma unroll
    for (int i = 0; i < 4; ++i)
#pragma unroll
        for (int j = 0; j < 8; ++j) acc[i][j] = 0.f;

    for (int kc = 0; kc < K; kc += 32) {
        __syncthreads();
#pragma unroll
        for (int it = 0; it < 2; ++it) {
            int idx = tid + it * 256;
            int r = idx >> 3, c4 = idx & 7;
            int gr = row0 + r;
            float4 v = make_float4(0.f, 0.f, 0.f, 0.f);
            if (gr < nrows) v = *(const float4*)(A + (size_t)gr * K + kc + c4 * 4);
            As_t[c4 * 4 + 0][r] = v.x;
            As_t[c4 * 4 + 1][r] = v.y;
            As_t[c4 * 4 + 2][r] = v.z;
            As_t[c4 * 4 + 3][r] = v.w;
        }
#pragma unroll
        for (int it = 0; it < 4; ++it) {
            int idx = tid + it * 256;
            int r = idx >> 5, c4 = idx & 31;
            *(float4*)(&Ws[r * 128 + c4 * 4]) = *(const float4*)(W + (size_t)(kc + r) * 128 + c4 * 4);
        }
        __syncthreads();
#pragma unroll
        for (int k = 0; k < 32; ++k) {
            float4 a4 = *(const float4*)(&As_t[k][tr * 4]);
            float a[4] = {a4.x, a4.y, a4.z, a4.w};
            float4 w0 = *(const float4*)(&Ws[k * 128 + c0]);
            float4 w1 = *(const float4*)(&Ws[k * 128 + c0 + 4]);
            float w[8] = {w0.x, w0.y, w0.z, w0.w, w1.x, w1.y, w1.z, w1.w};
#pragma unroll
            for (int i = 0; i < 4; ++i)
#pragma unroll
                for (int j = 0; j < 8; ++j) acc[i][j] += a[i] * w[j];
        }
    }
    float bv[8];
#pragma unroll
    for (int j = 0; j < 8; ++j) bv[j] = bias[c0 + j];
#pragma unroll
    for (int i = 0; i < 4; ++i) {
        int gr = row0 + tr * 4 + i;
        if (gr < nrows) {
            float o[8];
#pragma unroll
            for (int j = 0; j < 8; ++j) o[j] = fmaxf(acc[i][j] + bv[j], 0.f);
            __half2 p[4];
#pragma unroll
            for (int j = 0; j < 8; j += 2) p[j / 2] = __floats2half2_rn(o[j], o[j + 1]);
            *(float4*)(C16 + (size_t)gr * 128 + c0) = *(float4*)p;
        }
    }
}

// ---------- MFMA gate (LDS-B): gate[n] = relu(h16[n,:]@W16g^T + b1) . w2 + b2 ----------
__global__ __launch_bounds__(256) void k_gate_mfma(const __half* __restrict__ h16,
                                                   const __half* __restrict__ W16g,
                                                   const float* __restrict__ b1,
                                                   const float* __restrict__ w2,
                                                   const float* __restrict__ b2,
                                                   float* __restrict__ gate) {
    __shared__ __half Bs[64 * BPAD];
    int tid = threadIdx.x;
    int wave = tid >> 6, lane = tid & 63;
    int s = lane & 15, quad = lane >> 4;
    int row0 = blockIdx.x * 64 + wave * 16;
    int arow = row0 + s;
    if (arow >= N_NODES) arow = N_NODES - 1;

#pragma unroll
    for (int it = 0; it < 4; ++it) {
        int idx = tid + it * 256;
        int n = idx >> 4, ch = idx & 15;
        *(float4*)(&Bs[n * BPAD + ch * 8]) = *(const float4*)(W16g + (size_t)n * 128 + ch * 8);
    }
    __syncthreads();

    f32x4 acc[4];
#pragma unroll
    for (int c = 0; c < 4; ++c) acc[c] = (f32x4){0.f, 0.f, 0.f, 0.f};

    const __half* aptr = h16 + (size_t)arow * H;
#pragma unroll
    for (int kc = 0; kc < 128; kc += 32) {
        f16x8 afrag = *(const f16x8*)(aptr + kc + quad * 8);
#pragma unroll
        for (int c = 0; c < 4; ++c) {
            f16x8 bfrag = *(const f16x8*)(&Bs[(c * 16 + s) * BPAD + kc + quad * 8]);
            acc[c] = __builtin_amdgcn_mfma_f32_16x16x32_f16(afrag, bfrag, acc[c], 0, 0, 0);
        }
    }
    float part[4] = {0.f, 0.f, 0.f, 0.f};
#pragma unroll
    for (int c = 0; c < 4; ++c) {
        float bv = b1[c * 16 + s];
        float wv = w2[c * 16 + s];
#pragma unroll
        for (int i = 0; i < 4; ++i)
            part[i] += fmaxf(acc[c][i] + bv, 0.f) * wv;
    }
#pragma unroll
    for (int off = 1; off < 16; off <<= 1) {
#pragma unroll
        for (int i = 0; i < 4; ++i) part[i] += __shfl_xor(part[i], off);
    }
    if (s == 0) {
        float b2v = b2[0];
#pragma unroll
        for (int i = 0; i < 4; ++i) {
            int r = row0 + quad * 4 + i;
            if (r < N_NODES) gate[r] = part[i] + b2v;
        }
    }
}

// ---------- per-graph softmax over sorted batch ----------
__global__ __launch_bounds__(64) void k_softmax_g(float* __restrict__ gate,
                                                  const int* __restrict__ batch32,
                                                  float* __restrict__ gsum) {
    int g = blockIdx.x;
    int lane = threadIdx.x;
    int n0 = lower_bound(batch32, N_NODES, g);
    int n1 = lower_bound(batch32, N_NODES, g + 1);
    float m = -INFINITY;
    for (int n = n0 + lane; n < n1; n += 64) m = fmaxf(m, gate[n]);
#pragma unroll
    for (int off = 32; off >= 1; off >>= 1) m = fmaxf(m, __shfl_xor(m, off));
    float s = 0.f;
    for (int n = n0 + lane; n < n1; n += 64) {
        float e = expf(gate[n] - m);
        gate[n] = e;
        s += e;
    }
#pragma unroll
    for (int off = 32; off >= 1; off >>= 1) s += __shfl_xor(s, off);
    if (lane == 0) gsum[g] = s;
}

// ---------- per-graph pooling (no atomics, half2-vectorized, 4-row parallel) ----------
__global__ __launch_bounds__(256) void k_pool_g(const __half* __restrict__ h16,
                                                const float* __restrict__ eg,
                                                const float* __restrict__ gsum,
                                                const int* __restrict__ batch32,
                                                float* __restrict__ pooled) {
    __shared__ float sx[256], sy[256];
    int g = blockIdx.x;
    int tid = threadIdx.x;
    int c2 = tid & 63;              // col pair 2*c2, 2*c2+1
    int p = tid >> 6;               // 4-way row parallel
    int n0 = lower_bound(batch32, N_NODES, g);
    int n1 = lower_bound(batch32, N_NODES, g + 1);
    float ax = 0.f, ay = 0.f;
    for (int n = n0 + p; n < n1; n += 4) {
        __half2 v = *(const __half2*)(h16 + (size_t)n * H + c2 * 2);
        float2 fv = __half22float2(v);
        float w = eg[n];
        ax += w * fv.x;
        ay += w * fv.y;
    }
    sx[tid] = ax; sy[tid] = ay;
    __syncthreads();
    if (tid < 64) {
        float s = gsum[g];
        float vx = sx[tid] + sx[tid + 64] + sx[tid + 128] + sx[tid + 192];
        float vy = sy[tid] + sy[tid + 64] + sy[tid + 128] + sy[tid + 192];
        float2 o;
        o.x = (n1 > n0) ? vx / s : 0.f;
        o.y = (n1 > n0) ? vy / s : 0.f;
        *(float2*)(pooled + (size_t)g * H + c2 * 2) = o;
    }
}

// ---------- MFMA fused SAGE layer (LDS-B, staged epilogue; split from aggr) ----------
__global__ __launch_bounds__(256) void k_layer_mfma(const __half* __restrict__ t16,
                                                    __half* __restrict__ h16,
                                                    const __half* __restrict__ W16t,
                                                    const float* __restrict__ bl,
                                                    const float* __restrict__ g,
                                                    const float* __restrict__ bb) {
    __shared__ __half Bs[128 * BPAD];   // B-tile, then reused as output staging
    int tid = threadIdx.x;
    int wave = tid >> 6, lane = tid & 63;
    int s = lane & 15, quad = lane >> 4;
    int row0 = blockIdx.x * 64;
    int wrow0 = row0 + wave * 16;
    int arow = wrow0 + s;
    if (arow >= N_NODES) arow = N_NODES - 1;

    f32x4 acc[8];
#pragma unroll
    for (int c = 0; c < 8; ++c) acc[c] = (f32x4){0.f, 0.f, 0.f, 0.f};

#pragma unroll
    for (int ph = 0; ph < 2; ++ph) {
        __syncthreads();
#pragma unroll
        for (int it = 0; it < 8; ++it) {
            int idx = tid + it * 256;
            int n = idx >> 4, ch = idx & 15;
            *(float4*)(&Bs[n * BPAD + ch * 8]) =
                *(const float4*)(W16t + (size_t)n * 256 + ph * 128 + ch * 8);
        }
        __syncthreads();
        const __half* aptr = (ph ? h16 : t16) + (size_t)arow * H;
#pragma unroll
        for (int kk = 0; kk < 128; kk += 32) {
            f16x8 afrag = *(const f16x8*)(aptr + kk + quad * 8);
#pragma unroll
            for (int c = 0; c < 8; ++c) {
                f16x8 bfrag = *(const f16x8*)(&Bs[(c * 16 + s) * BPAD + kk + quad * 8]);
                acc[c] = __builtin_amdgcn_mfma_f32_16x16x32_f16(afrag, bfrag, acc[c], 0, 0, 0);
            }
        }
    }

    float y[8][4];
    float sm[4] = {0.f, 0.f, 0.f, 0.f}, sq[4] = {0.f, 0.f, 0.f, 0.f};
#pragma unroll
    for (int c = 0; c < 8; ++c) {
        float bv = bl[c * 16 + s];
#pragma unroll
        for (int i = 0; i < 4; ++i) {
            float v = acc[c][i] + bv;
            y[c][i] = v;
            sm[i] += v;
            sq[i] += v * v;
        }
    }
#pragma unroll
    for (int off = 1; off < 16; off <<= 1) {
#pragma unroll
        for (int i = 0; i < 4; ++i) {
            sm[i] += __shfl_xor(sm[i], off);
            sq[i] += __shfl_xor(sq[i], off);
        }
    }
    float mean[4], rstd[4];
#pragma unroll
    for (int i = 0; i < 4; ++i) {
        mean[i] = sm[i] * (1.0f / H);
        float var = sq[i] * (1.0f / H) - mean[i] * mean[i];
        rstd[i] = rsqrtf(var + LN_EPS);
    }
    float gv[8], bbv[8];
#pragma unroll
    for (int c = 0; c < 8; ++c) { gv[c] = g[c * 16 + s]; bbv[c] = bb[c * 16 + s]; }

    __syncthreads();
#pragma unroll
    for (int i = 0; i < 4; ++i) {
        int lr = wave * 16 + quad * 4 + i;
#pragma unroll
        for (int c = 0; c < 8; ++c) {
            float yv = (y[c][i] - mean[i]) * rstd[i] * gv[c] + bbv[c];
            yv = yv > 0.f ? yv : expf(yv) - 1.f;
            Bs[lr * BPAD + c * 16 + s] = __float2half(yv);
        }
    }
    __syncthreads();
#pragma unroll
    for (int it = 0; it < 4; ++it) {
        int idx = tid + it * 256;
        int r = idx >> 4, ch = idx & 15;
        int grow = row0 + r;
        if (grow < N_NODES) {
            float4 sv = *(float4*)(&Bs[r * BPAD + ch * 8]);
            float4 hv = *(const float4*)(h16 + (size_t)grow * H + ch * 8);
            __half2* pa = (__half2*)&sv;
            const __half2* pb = (const __half2*)&hv;
#pragma unroll
            for (int j = 0; j < 4; ++j) {
                float2 fa = __half22float2(pa[j]);
                float2 fb = __half22float2(pb[j]);
                pa[j] = __floats2half2_rn(fa.x + fb.x, fa.y + fb.y);
            }
            *(float4*)(h16 + (size_t)grow * H + ch * 8) = sv;
        }
    }
}

// ---------- mean aggregation: TWO nodes/wave, padded implicit CSR, branchless ----------
// Rounds per node: 1.5 (one int2 deg load + one 4x int4 col round + 16 gathers
// per TWO nodes). No rowptr, no clamps/selects — padding slots hold the zero-row
// offset (exact +0.0). Rare chunk2 (deg>32) is a wave-uniform branch.
__global__ __launch_bounds__(256) void k_aggr(const __half* __restrict__ h16,
                                              const int* __restrict__ degarr,
                                              const int* __restrict__ colp,
                                              __half* __restrict__ t16) {
    int lane = threadIdx.x & 63;
    int wid = blockIdx.x * 4 + (threadIdx.x >> 6);   // 50000 waves exactly
    int n0 = wid * 2;                                // covers 0..99998; n1 = n0+1
    int s = lane & 15, g = lane >> 4;
    int soff = s * 16;

    int2 dd = *(const int2*)(degarr + n0);
    const int* cpA = colp + ((size_t)n0 << 6) + (g << 4);
    const int* cpB = cpA + 64;
    int4 ca0 = *(const int4*)cpA;
    int4 ca1 = *(const int4*)(cpA + 4);
    int4 cb0 = *(const int4*)cpB;
    int4 cb1 = *(const int4*)(cpB + 4);
    __builtin_amdgcn_sched_barrier(0);

    f32x4 rv[16];
    rv[0]  = gload16(h16, ca0.x + soff);
    rv[1]  = gload16(h16, ca0.y + soff);
    rv[2]  = gload16(h16, ca0.z + soff);
    rv[3]  = gload16(h16, ca0.w + soff);
    rv[4]  = gload16(h16, ca1.x + soff);
    rv[5]  = gload16(h16, ca1.y + soff);
    rv[6]  = gload16(h16, ca1.z + soff);
    rv[7]  = gload16(h16, ca1.w + soff);
    rv[8]  = gload16(h16, cb0.x + soff);
    rv[9]  = gload16(h16, cb0.y + soff);
    rv[10] = gload16(h16, cb0.z + soff);
    rv[11] = gload16(h16, cb0.w + soff);
    rv[12] = gload16(h16, cb1.x + soff);
    rv[13] = gload16(h16, cb1.y + soff);
    rv[14] = gload16(h16, cb1.z + soff);
    rv[15] = gload16(h16, cb1.w + soff);
    asm volatile("s_waitcnt vmcnt(0)" ::: "memory");
    __builtin_amdgcn_sched_barrier(0);

    __half2 z = __floats2half2_rn(0.f, 0.f);
    __half2 acA[4][4], acB[4][4];
#pragma unroll
    for (int a = 0; a < 4; ++a)
#pragma unroll
        for (int k = 0; k < 4; ++k) { acA[a][k] = z; acB[a][k] = z; }

#pragma unroll
    for (int j = 0; j < 8; ++j) {
        const __half2* hvA = (const __half2*)&rv[j];
        const __half2* hvB = (const __half2*)&rv[8 + j];
        int a = j & 3;
#pragma unroll
        for (int k = 0; k < 4; ++k) {
            acA[a][k] = __hadd2(acA[a][k], hvA[k]);
            acB[a][k] = __hadd2(acB[a][k], hvB[k]);
        }
    }

    // rare chunk2: edges 32..63 (deg>32: p ~ 1e-4 per node)
    if ((dd.x > 32) || (dd.y > 32)) {
        int4 ca2 = *(const int4*)(cpA + 8);
        int4 ca3 = *(const int4*)(cpA + 12);
        int4 cb2 = *(const int4*)(cpB + 8);
        int4 cb3 = *(const int4*)(cpB + 12);
        __builtin_amdgcn_sched_barrier(0);
        f32x4 rw[16];
        rw[0]  = gload16(h16, ca2.x + soff);
        rw[1]  = gload16(h16, ca2.y + soff);
        rw[2]  = gload16(h16, ca2.z + soff);
        rw[3]  = gload16(h16, ca2.w + soff);
        rw[4]  = gload16(h16, ca3.x + soff);
        rw[5]  = gload16(h16, ca3.y + soff);
        rw[6]  = gload16(h16, ca3.z + soff);
        rw[7]  = gload16(h16, ca3.w + soff);
        rw[8]  = gload16(h16, cb2.x + soff);
        rw[9]  = gload16(h16, cb2.y + soff);
        rw[10] = gload16(h16, cb2.z + soff);
        rw[11] = gload16(h16, cb2.w + soff);
        rw[12] = gload16(h16, cb3.x + soff);
        rw[13] = gload16(h16, cb3.y + soff);
        rw[14] = gload16(h16, cb3.z + soff);
        rw[15] = gload16(h16, cb3.w + soff);
        asm volatile("s_waitcnt vmcnt(0)" ::: "memory");
        __builtin_amdgcn_sched_barrier(0);
#pragma unroll
        for (int j = 0; j < 8; ++j) {
            const __half2* hvA = (const __half2*)&rw[j];
            const __half2* hvB = (const __half2*)&rw[8 + j];
            int a = j & 3;
#pragma unroll
            for (int k = 0; k < 4; ++k) {
                acA[a][k] = __hadd2(acA[a][k], hvA[k]);
                acB[a][k] = __hadd2(acB[a][k], hvB[k]);
            }
        }
    }

    // combine 4 fp16 streams in fp32, reduce across the 4 edge subgroups, store
    float fA[8], fB[8];
#pragma unroll
    for (int k = 0; k < 4; ++k) {
        float2 a0 = __half22float2(acA[0][k]);
        float2 a1 = __half22float2(acA[1][k]);
        float2 a2 = __half22float2(acA[2][k]);
        float2 a3 = __half22float2(acA[3][k]);
        fA[2 * k]     = (a0.x + a1.x) + (a2.x + a3.x);
        fA[2 * k + 1] = (a0.y + a1.y) + (a2.y + a3.y);
        float2 b0 = __half22float2(acB[0][k]);
        float2 b1 = __half22float2(acB[1][k]);
        float2 b2 = __half22float2(acB[2][k]);
        float2 b3 = __half22float2(acB[3][k]);
        fB[2 * k]     = (b0.x + b1.x) + (b2.x + b3.x);
        fB[2 * k + 1] = (b0.y + b1.y) + (b2.y + b3.y);
    }
#pragma unroll
    for (int off = 16; off <= 32; off <<= 1) {
#pragma unroll
        for (int k = 0; k < 8; ++k) {
            fA[k] += __shfl_xor(fA[k], off);
            fB[k] += __shfl_xor(fB[k], off);
        }
    }
    if (g == 0) {
        float invA = 1.0f / (float)(dd.x > 1 ? dd.x : 1);
        float invB = 1.0f / (float)(dd.y > 1 ? dd.y : 1);
        __half2 oA[4], oB[4];
#pragma unroll
        for (int k = 0; k < 4; ++k) {
            oA[k] = __floats2half2_rn(fA[2 * k] * invA, fA[2 * k + 1] * invA);
            oB[k] = __floats2half2_rn(fB[2 * k] * invB, fB[2 * k + 1] * invB);
        }
        *(float4*)(t16 + (size_t)n0 * H + s * 8) = *(float4*)oA;
        *(float4*)(t16 + (size_t)(n0 + 1) * H + s * 8) = *(float4*)oB;
    }
}

// ---------- classifier ----------
__global__ __launch_bounds__(64) void k_cls(const float* __restrict__ pooled,
                                            const float* __restrict__ w1,
                                            const float* __restrict__ b1,
                                            const float* __restrict__ w2,
                                            const float* __restrict__ b2,
                                            float* __restrict__ out) {
    __shared__ float sp[64];
    int g = blockIdx.x;
    int lane = threadIdx.x;
    float r0 = pooled[(size_t)g * H + lane];
    float r1 = pooled[(size_t)g * H + 64 + lane];
    float acc = b1[lane];
#pragma unroll 16
    for (int k = 0; k < 64; ++k) acc += __shfl(r0, k) * w1[k * 64 + lane];
#pragma unroll 16
    for (int k = 0; k < 64; ++k) acc += __shfl(r1, k) * w1[(64 + k) * 64 + lane];
    sp[lane] = fmaxf(acc, 0.f);
    __syncthreads();
    if (lane < NUM_CLASSES) {
        float o = b2[lane];
        for (int c = 0; c < 64; ++c) o += sp[c] * w2[c * NUM_CLASSES + lane];
        out[g * NUM_CLASSES + lane] = o;
    }
}

extern "C" void kernel_launch(void* const* d_in, const int* in_sizes, int n_in,
                              void* d_out, int out_size, void* d_ws, size_t ws_size,
                              hipStream_t stream) {
    const float* x       = (const float*)d_in[0];
    const int*   eraw    = (const int*)d_in[1];
    const int*   braw    = (const int*)d_in[2];
    const float* proj_w  = (const float*)d_in[3];
    const float* proj_b  = (const float*)d_in[4];
    const float* lin_l_w = (const float*)d_in[5];
    const float* lin_l_b = (const float*)d_in[6];
    const float* lin_r_w = (const float*)d_in[7];
    const float* ln_g    = (const float*)d_in[8];
    const float* ln_b    = (const float*)d_in[9];
    const float* gate_w1 = (const float*)d_in[10];
    const float* gate_b1 = (const float*)d_in[11];
    const float* gate_w2 = (const float*)d_in[12];
    const float* gate_b2 = (const float*)d_in[13];
    const float* cls_w1  = (const float*)d_in[14];
    const float* cls_b1  = (const float*)d_in[15];
    const float* cls_w2  = (const float*)d_in[16];
    const float* cls_b2  = (const float*)d_in[17];
    float* out = (float*)d_out;

    // workspace layout
    __half* h16    = (__half*)d_ws;                       // N*H f16
    __half* t16    = h16 + (size_t)N_NODES * H;           // N*H f16
    float*  gate   = (float*)(t16 + (size_t)N_NODES * H); // N (first 256B double as aggr zero-row)
    float*  gsum   = gate + N_NODES;                      // 512
    float*  pooled = gsum + NUM_GRAPHS;                   // 512*H
    __half* W16t   = (__half*)(pooled + NUM_GRAPHS * H);  // 3*128*256
    __half* W16g   = W16t + (size_t)NUM_LAYERS * 32768;   // 64*128
    int* flags     = (int*)(W16g + 64 * 128);             // 4
    int* degarr    = flags + 4;                           // N
    int* colp      = degarr + N_NODES;                    // N*64 padded col (byte offsets)
    int* batch32   = colp + (size_t)N_NODES * 64;         // N
    int* bcnt      = batch32 + N_NODES;                   // 512
    int* boff      = bcnt + 512;                          // 513
    int* bcursor   = boff + 513;                          // 512
    unsigned int* br = (unsigned int*)(bcursor + 512);    // E packed records

    const int zoff = (int)((const char*)gate - (const char*)h16);  // zero-row byte offset

    const int nbN = (N_NODES + 255) / 256;
    const int nbE4 = (N_EDGES + EPB - 1) / EPB;           // 391
    const int nbW2 = 12500;                               // 2 nodes/wave, exact cover
    const int nbG = (N_NODES + 63) / 64;                  // 1563
    const int nbP = (NUM_LAYERS * 128 * 256 + 64 * 128 + 255) / 256;

    k_detect<<<2, 256, 0, stream>>>(eraw, braw, flags, bcnt, gate);
    k_conv_batch<<<nbN, 256, 0, stream>>>(braw, flags, batch32);
    // CSR build: hist -> scan -> bucket -> padded tail (deg + padded col)
    k_bhist<<<512, 256, 0, stream>>>(eraw, flags, bcnt);
    k_bscan<<<1, 512, 0, stream>>>(bcnt, boff, bcursor);
    k_bucket<<<nbE4, 256, 0, stream>>>(eraw, flags, bcursor, br);
    k_csr_tail<<<NBKT, 256, 0, stream>>>(br, boff, degarr, colp, zoff);
    // weights to fp16 transposed
    k_prepw<<<nbP, 256, 0, stream>>>(lin_l_w, lin_r_w, gate_w1, W16t, W16g);

    // h16 = fp16(relu(x @ proj_w + proj_b))
    k_gemm_proj<<<nbG, 256, 0, stream>>>(x, proj_w, proj_b, h16, N_NODES, NDIM);

    for (int l = 0; l < NUM_LAYERS; ++l) {
        const float* bl  = lin_l_b + (size_t)l * H;
        const float* gl  = ln_g + (size_t)l * H;
        const float* blb = ln_b + (size_t)l * H;
        k_aggr<<<nbW2, 256, 0, stream>>>(h16, degarr, colp, t16);
        k_layer_mfma<<<nbG, 256, 0, stream>>>(t16, h16, W16t + (size_t)l * 32768, bl, gl, blb);
    }

    // gate -> per-graph softmax -> per-graph pooling -> classifier
    k_gate_mfma<<<nbG, 256, 0, stream>>>(h16, W16g, gate_b1, gate_w2, gate_b2, gate);
    k_softmax_g<<<NUM_GRAPHS, 64, 0, stream>>>(gate, batch32, gsum);
    k_pool_g<<<NUM_GRAPHS, 256, 0, stream>>>(h16, gate, gsum, batch32, pooled);
    k_cls<<<NUM_GRAPHS, 64, 0, stream>>>(pooled, cls_w1, cls_b1, cls_w2, cls_b2, out);
}